// Round 15
// baseline (16407.462 us; speedup 1.0000x reference)
//
#include <hip/hip_runtime.h>
#include <cstddef>
#include <cstdint>

typedef __attribute__((ext_vector_type(8))) short short8v;
typedef __attribute__((ext_vector_type(4))) float f32x4;

__device__ __forceinline__ float sigmf(float x) { return 1.0f / (1.0f + __expf(-x)); }

__device__ __forceinline__ unsigned short bf16_rn(float x) {
    union { float f; unsigned u; } v; v.f = x;
    unsigned r = v.u + 0x7FFF + ((v.u >> 16) & 1);
    return (unsigned short)(r >> 16);
}
__device__ __forceinline__ float bf16_to_f(unsigned short h) {
    union { unsigned u; float f; } v; v.u = ((unsigned)h) << 16; return v.f;
}
__device__ __forceinline__ unsigned long long pack4(unsigned short a, unsigned short b,
                                                    unsigned short c, unsigned short d) {
    return (unsigned long long)a | ((unsigned long long)b << 16)
         | ((unsigned long long)c << 32) | ((unsigned long long)d << 48);
}

#define MFMA_(d, va, vb) d = __builtin_amdgcn_mfma_f32_16x16x32_bf16(va, vb, d, 0, 0, 0)

#define AT_LD(p)        __hip_atomic_load((p), __ATOMIC_RELAXED, __HIP_MEMORY_SCOPE_AGENT)
#define AT_ST(p, v)     __hip_atomic_store((p), (v), __ATOMIC_RELAXED, __HIP_MEMORY_SCOPE_AGENT)
#define AT_ST_REL(p, v) __hip_atomic_store((p), (v), __ATOMIC_RELEASE, __HIP_MEMORY_SCOPE_AGENT)
#define AT_ADD(p, v)    __hip_atomic_fetch_add((p), (v), __ATOMIC_RELAXED, __HIP_MEMORY_SCOPE_AGENT)

// ---------------------------------------------------------------------------
// Fragment layout (A and W): F[p][rgw][kf][l][e]; rgw=r>>4, kf=k>>5,
// l=((k>>3)&3)*16+(r&15), e=k&7. Per-(p,rgw) chunk = 32*64*8 = 16384 shorts.
// ---------------------------------------------------------------------------
__device__ __forceinline__ void write_frag3_nt(unsigned short* __restrict__ dst, int NRGW,
                                               int r, int k, float x)
{
    unsigned short hi = bf16_rn(x); float r1 = x - bf16_to_f(hi);
    unsigned short md = bf16_rn(r1);
    unsigned short lo = bf16_rn(r1 - bf16_to_f(md));
    int base = (((r >> 4) * 32 + (k >> 5)) * 64 + ((k >> 3) & 3) * 16 + (r & 15)) * 8 + (k & 7);
    int ps = NRGW * 16384;
    __builtin_nontemporal_store(hi, &dst[base]);
    __builtin_nontemporal_store(md, &dst[ps + base]);
    __builtin_nontemporal_store(lo, &dst[2 * ps + base]);
}

__launch_bounds__(256)
__global__ void rearr_frag(const float* __restrict__ src, int ld, int c0,
                           unsigned short* __restrict__ dst, int R, int K)
{
    int idx = blockIdx.x * 256 + threadIdx.x;
    int kpr = K >> 3;
    if (idx >= R * kpr) return;
    int r = idx / kpr, k = (idx % kpr) * 8;
    int NRGW = R >> 4;
    const float* s = src + (size_t)r * ld + c0 + k;
    float4 v0 = *(const float4*)s, v1 = *(const float4*)(s + 4);
    float xs[8] = {v0.x, v0.y, v0.z, v0.w, v1.x, v1.y, v1.z, v1.w};
    unsigned short hi[8], md[8], lo[8];
#pragma unroll
    for (int e = 0; e < 8; ++e) {
        hi[e] = bf16_rn(xs[e]); float r1 = xs[e] - bf16_to_f(hi[e]);
        md[e] = bf16_rn(r1);
        lo[e] = bf16_rn(r1 - bf16_to_f(md[e]));
    }
    int base = (((r >> 4) * 32 + (k >> 5)) * 64 + ((k >> 3) & 3) * 16 + (r & 15)) * 8;
    size_t ps = (size_t)NRGW * 16384;
    *(unsigned long long*)&dst[base]          = pack4(hi[0], hi[1], hi[2], hi[3]);
    *(unsigned long long*)&dst[base + 4]      = pack4(hi[4], hi[5], hi[6], hi[7]);
    *(unsigned long long*)&dst[ps + base]     = pack4(md[0], md[1], md[2], md[3]);
    *(unsigned long long*)&dst[ps + base + 4] = pack4(md[4], md[5], md[6], md[7]);
    *(unsigned long long*)&dst[2*ps + base]     = pack4(lo[0], lo[1], lo[2], lo[3]);
    *(unsigned long long*)&dst[2*ps + base + 4] = pack4(lo[4], lo[5], lo[6], lo[7]);
}

// ---------------------------------------------------------------------------
// Two-level tree barrier; gidx = this block's group, ng groups, bpg blocks ea.
// ---------------------------------------------------------------------------
__device__ __forceinline__ void tree_barrier(unsigned* bar, int gidx, int ng, int bpg)
{
    __syncthreads();
    if (threadIdx.x == 0) {
        unsigned* gcnt = bar + gidx * 32;
        unsigned* ggen = bar + gidx * 32 + 1;
        unsigned* rcnt = bar + ng * 32;
        unsigned* rgen = bar + ng * 32 + 1;
        __threadfence();   // release
        unsigned mygen = AT_LD(ggen);
        unsigned prev = AT_ADD(gcnt, 1u);
        if (prev == (unsigned)(bpg - 1)) {
            AT_ST(gcnt, 0u);
            unsigned rg = AT_LD(rgen);
            unsigned rprev = AT_ADD(rcnt, 1u);
            if (rprev == (unsigned)(ng - 1)) {
                AT_ST(rcnt, 0u);
                AT_ST_REL(rgen, rg + 1u);
            } else {
                while (AT_LD(rgen) == rg) __builtin_amdgcn_s_sleep(1);
            }
            AT_ST_REL(ggen, mygen + 1u);
        } else {
            while (AT_LD(ggen) == mygen) __builtin_amdgcn_s_sleep(1);
        }
        __threadfence();   // acquire
    }
    __syncthreads();
}

// ---------------------------------------------------------------------------
// Batched fp32 GEMM via bf16-split MFMA (validated R3): C = A@W^T + bias.
// ---------------------------------------------------------------------------
template <int NS>
__launch_bounds__(256, 2)
__global__ void gemm_mfma_split(const float* __restrict__ A, int lda,
                                const float* __restrict__ W, int ldw,
                                float* __restrict__ C, int ldc,
                                const float* __restrict__ bias,
                                int M, int N, int K)
{
    __shared__ unsigned short Abf[NS][128][40];
    __shared__ unsigned short Bbf[NS][128][40];
    const int tid = threadIdx.x;
    const int m0 = blockIdx.y * 128, n0 = blockIdx.x * 128;
    const int wave = tid >> 6, lane = tid & 63;
    const int wr = wave >> 1, wc = wave & 1;
    const int lr = lane & 15, lk = (lane >> 4) * 8;

    f32x4 acc[4][4];
#pragma unroll
    for (int i = 0; i < 4; ++i)
#pragma unroll
        for (int j = 0; j < 4; ++j) acc[i][j] = (f32x4){0.f, 0.f, 0.f, 0.f};

    const int arow = tid >> 1;
    const int akh  = (tid & 1) * 16;
    int gr = m0 + arow; if (gr > M - 1) gr = M - 1;
    int gn = n0 + arow; if (gn > N - 1) gn = N - 1;
    const float* aptr = A + (size_t)gr * lda + akh;
    const float* wptr = W + (size_t)gn * ldw + akh;

    for (int k0 = 0; k0 < K; k0 += 32) {
#pragma unroll
        for (int q = 0; q < 4; ++q) {
            float4 v = *(const float4*)(aptr + k0 + q * 4);
            float xs[4] = {v.x, v.y, v.z, v.w};
            unsigned short h[4], hm[4], hl[4];
#pragma unroll
            for (int e = 0; e < 4; ++e) {
                h[e] = bf16_rn(xs[e]);
                if (NS == 3) {
                    float r1 = xs[e] - bf16_to_f(h[e]);
                    hm[e] = bf16_rn(r1);
                    hl[e] = bf16_rn(r1 - bf16_to_f(hm[e]));
                }
            }
            *(unsigned long long*)&Abf[0][arow][akh + q * 4] = pack4(h[0], h[1], h[2], h[3]);
            if (NS == 3) {
                *(unsigned long long*)&Abf[1][arow][akh + q * 4] = pack4(hm[0], hm[1], hm[2], hm[3]);
                *(unsigned long long*)&Abf[2][arow][akh + q * 4] = pack4(hl[0], hl[1], hl[2], hl[3]);
            }
        }
#pragma unroll
        for (int q = 0; q < 4; ++q) {
            float4 v = *(const float4*)(wptr + k0 + q * 4);
            float xs[4] = {v.x, v.y, v.z, v.w};
            unsigned short h[4], hm[4], hl[4];
#pragma unroll
            for (int e = 0; e < 4; ++e) {
                h[e] = bf16_rn(xs[e]);
                if (NS == 3) {
                    float r1 = xs[e] - bf16_to_f(h[e]);
                    hm[e] = bf16_rn(r1);
                    hl[e] = bf16_rn(r1 - bf16_to_f(hm[e]));
                }
            }
            *(unsigned long long*)&Bbf[0][arow][akh + q * 4] = pack4(h[0], h[1], h[2], h[3]);
            if (NS == 3) {
                *(unsigned long long*)&Bbf[1][arow][akh + q * 4] = pack4(hm[0], hm[1], hm[2], hm[3]);
                *(unsigned long long*)&Bbf[2][arow][akh + q * 4] = pack4(hl[0], hl[1], hl[2], hl[3]);
            }
        }
        __syncthreads();

        short8v a[NS][4], b[4];
#pragma unroll
        for (int p = 0; p < NS; ++p)
#pragma unroll
            for (int i = 0; i < 4; ++i)
                a[p][i] = *(const short8v*)&Abf[p][wr * 64 + i * 16 + lr][lk];
#pragma unroll
        for (int q = 0; q < NS; ++q) {
#pragma unroll
            for (int j = 0; j < 4; ++j)
                b[j] = *(const short8v*)&Bbf[q][wc * 64 + j * 16 + lr][lk];
            const int pmax = (NS == 1) ? 1 : (3 - q);
#pragma unroll
            for (int p = 0; p < 3; ++p) {
                if (p >= pmax) break;
#pragma unroll
                for (int i = 0; i < 4; ++i)
#pragma unroll
                    for (int j = 0; j < 4; ++j)
                        acc[i][j] = __builtin_amdgcn_mfma_f32_16x16x32_bf16(
                            a[p][i], b[j], acc[i][j], 0, 0, 0);
            }
        }
        __syncthreads();
    }

    const int crow = (lane >> 4) * 4;
#pragma unroll
    for (int i = 0; i < 4; ++i) {
        int mbase = m0 + wr * 64 + i * 16 + crow;
#pragma unroll
        for (int j = 0; j < 4; ++j) {
            int n = n0 + wc * 64 + j * 16 + lr;
            if (n < N) {
                float bv = bias[n];
#pragma unroll
                for (int r = 0; r < 4; ++r) {
                    int m = mbase + r;
                    if (m < M) C[(size_t)m * ldc + n] = acc[i][j][r] + bv;
                }
            }
        }
    }
}

__launch_bounds__(256)
__global__ void zero_f(float* __restrict__ p, int n)
{
    int i = blockIdx.x * 256 + threadIdx.x;
    if (i < n) p[i] = 0.f;
}

__launch_bounds__(256)
__global__ void vec_add2(const float* __restrict__ a, const float* __restrict__ b,
                         float* __restrict__ o, int n)
{
    int i = blockIdx.x * 256 + threadIdx.x;
    if (i < n) o[i] = a[i] + b[i];
}

__launch_bounds__(256)
__global__ void sample0_fill(const float* __restrict__ emW, const float* __restrict__ emb,
                             float* __restrict__ samples)
{
    int idx = blockIdx.x * 256 + threadIdx.x; // 65536
    int d = idx & 1023;
    samples[idx] = emW[(size_t)d * 20000 + 19998] + emb[d];
}

// stage one rg-chunk (96KB) of a 64-row frag buffer into LDS
__device__ __forceinline__ void stage_A(unsigned short* __restrict__ LDSA,
                                        const unsigned short* __restrict__ src,
                                        int rg, int tid)
{
#pragma unroll
    for (int p = 0; p < 3; ++p) {
        const unsigned short* sp = src + (size_t)(p * 4 + rg) * 16384;
        unsigned short* dp = LDSA + p * 16384;
#pragma unroll
        for (int it = 0; it < 4; ++it) {
            int idx = tid + it * 512;
            *(short8v*)&dp[idx * 8] = *(const short8v*)&sp[idx * 8];
        }
    }
}

// 16-kf MFMA block from LDSA rg-chunk vs wreg (encoder-style, in-block gates)
__device__ __forceinline__ f32x4 mfma16(const unsigned short* __restrict__ LDSA,
                                        const short8v* __restrict__ wreg,
                                        int kh, int lane)
{
    f32x4 acc0 = (f32x4){0.f,0.f,0.f,0.f}, acc1 = acc0;
#pragma unroll
    for (int i = 0; i < 16; ++i) {
        int kf = kh * 16 + i;
        short8v a0 = *(const short8v*)&LDSA[(kf * 64 + lane) * 8];
        short8v a1 = *(const short8v*)&LDSA[16384 + (kf * 64 + lane) * 8];
        short8v a2 = *(const short8v*)&LDSA[32768 + (kf * 64 + lane) * 8];
        short8v b0 = wreg[i * 3 + 0], b1 = wreg[i * 3 + 1], b2 = wreg[i * 3 + 2];
        f32x4& A = (i & 1) ? acc1 : acc0;
        MFMA_(A, a0, b0); MFMA_(A, a0, b1); MFMA_(A, a1, b0);
        MFMA_(A, a1, b1); MFMA_(A, a0, b2); MFMA_(A, a2, b0);
    }
    return acc0 + acc1;
}

// ---------------------------------------------------------------------------
// k1: encoder real steps 0..79. 256 blocks x 512. 1 barrier/step.
// XCD-local rg: rg = bid&3. waves_per_eu(1) -> allow 256-VGPR alloc (wreg[48]).
// ---------------------------------------------------------------------------
__launch_bounds__(512, 1)
__attribute__((amdgpu_waves_per_eu(1, 2)))
__global__ void coop_enc80(const unsigned short* __restrict__ WencF,
                           const float* __restrict__ Xbig,
                           unsigned short* __restrict__ hfrag,   // 2 bufs x 196608
                           float* __restrict__ enc_seq,
                           float* __restrict__ cglobE,
                           unsigned* __restrict__ bar)
{
    __shared__ unsigned short LDSA[3 * 16384];
    __shared__ float gbuf[8][16][16];
    const int bid = blockIdx.x, tid = threadIdx.x;
    const int w = tid >> 6, lane = tid & 63;
    const int g = w & 3, kh = w >> 2;
    const int rg = bid & 3, cg = bid >> 2;
    const int wbase = g * 64 + cg;
    const int r_l = (tid & 255) >> 4, c_l = tid & 15;
    const int row = rg * 16 + r_l, col = cg * 16 + c_l;
    float cstate = 0.f;

    short8v wreg[48];
#pragma unroll
    for (int i = 0; i < 16; ++i) {
        int kf = kh * 16 + i;
#pragma unroll
        for (int p = 0; p < 3; ++p)
            wreg[i * 3 + p] = *(const short8v*)&WencF[((size_t)(p * 256 + wbase) * 32 + kf) * 512 + lane * 8];
    }

    float pf[4];
    if (tid < 256) {
#pragma unroll
        for (int g2 = 0; g2 < 4; ++g2)
            pf[g2] = Xbig[(size_t)row * 4096 + g2 * 1024 + col];
    }

    for (int s = 0; s < 80; ++s) {
        const unsigned short* hf = hfrag + (s & 1) * 196608;
        stage_A(LDSA, hf, rg, tid);
        __syncthreads();
        f32x4 acc = mfma16(LDSA, wreg, kh, lane);
#pragma unroll
        for (int r = 0; r < 4; ++r)
            gbuf[w][(lane >> 4) * 4 + r][lane & 15] = acc[r];
        __syncthreads();

        if (tid < 256) {
            float gv[4];
#pragma unroll
            for (int g2 = 0; g2 < 4; ++g2)
                gv[g2] = gbuf[g2][r_l][c_l] + gbuf[4 + g2][r_l][c_l] + pf[g2];
            float cn = sigmf(gv[1]) * cstate + sigmf(gv[0]) * tanhf(gv[2]);
            float hn = sigmf(gv[3]) * tanhf(cn);
            cstate = cn;
            __builtin_nontemporal_store(hn, &enc_seq[(size_t)s * 65536 + row * 1024 + col]);
            write_frag3_nt(hfrag + ((s + 1) & 1) * 196608, 4, row, col, hn);
            if (s == 79) __builtin_nontemporal_store(cstate, &cglobE[row * 1024 + col]);
            else {
#pragma unroll
                for (int g2 = 0; g2 < 4; ++g2)
                    pf[g2] = Xbig[((size_t)(s + 1) * 64 + row) * 4096 + g2 * 1024 + col];
            }
        }
        tree_barrier(bar, bid >> 5, 8, 32);
    }
}

// ---------------------------------------------------------------------------
// k3: enc-pad (blocks 0..127) CONCURRENT WITH dec warm-up (blocks 128..255).
// XCD-local rg2 = lb&1. waves_per_eu(1) to avoid wreg[48] spill.
// ---------------------------------------------------------------------------
__launch_bounds__(512, 1)
__attribute__((amdgpu_waves_per_eu(1, 2)))
__global__ void coop_padwarm(const unsigned short* __restrict__ WencF,
                             const unsigned short* __restrict__ WdecF,
                             const float* __restrict__ benc,
                             const float* __restrict__ Xwarm,
                             const float* __restrict__ cglobE,
                             unsigned short* __restrict__ hfragE,
                             unsigned short* __restrict__ hfragD,
                             float* __restrict__ enc_pad,
                             float* __restrict__ cglobD,
                             float* __restrict__ h_fp32,
                             unsigned* __restrict__ barE,
                             unsigned* __restrict__ barW)
{
    __shared__ unsigned short LDSA[3 * 16384];
    __shared__ float gbuf[8][16][16];
    const int bid = blockIdx.x, tid = threadIdx.x;
    const int w = tid >> 6, lane = tid & 63;
    const int g = w & 3, kh = w >> 2;
    const bool isW = bid >= 128;
    const int lb = bid & 127;
    const int rg2 = lb & 1, cg = lb >> 1;
    const int wbase = g * 64 + cg;
    const int r_l = (tid & 255) >> 4, c_l = tid & 15;
    const int col = cg * 16 + c_l;
    const unsigned short* Wf = isW ? WdecF : WencF;
    unsigned short* hfrag = isW ? hfragD : hfragE;
    unsigned* bar = isW ? barW : barE;

    short8v wreg[48];
#pragma unroll
    for (int i = 0; i < 16; ++i) {
        int kf = kh * 16 + i;
#pragma unroll
        for (int p = 0; p < 3; ++p)
            wreg[i * 3 + p] = *(const short8v*)&Wf[((size_t)(p * 256 + wbase) * 32 + kf) * 512 + lane * 8];
    }

    float cst[2] = {0.f, 0.f};
    float pfx[2][4];
    if (tid < 256) {
#pragma unroll
        for (int l = 0; l < 2; ++l) {
            int row = rg2 * 32 + l * 16 + r_l;
            if (!isW) cst[l] = cglobE[row * 1024 + col];
#pragma unroll
            for (int g2 = 0; g2 < 4; ++g2)
                pfx[l][g2] = isW ? Xwarm[(size_t)row * 4096 + g2 * 1024 + col]
                                 : benc[g2 * 1024 + col];
        }
    }

    for (int s = 0; s < 80; ++s) {
        const unsigned short* hf = hfrag + (s & 1) * 196608;
        unsigned short* hout = hfrag + ((s + 1) & 1) * 196608;
#pragma unroll
        for (int l = 0; l < 2; ++l) {
            const int rgi = rg2 * 2 + l;
            stage_A(LDSA, hf, rgi, tid);
            __syncthreads();
            f32x4 acc = mfma16(LDSA, wreg, kh, lane);
#pragma unroll
            for (int r = 0; r < 4; ++r)
                gbuf[w][(lane >> 4) * 4 + r][lane & 15] = acc[r];
            __syncthreads();
            if (tid < 256) {
                const int row = rgi * 16 + r_l;
                float gv[4];
#pragma unroll
                for (int g2 = 0; g2 < 4; ++g2)
                    gv[g2] = gbuf[g2][r_l][c_l] + gbuf[4 + g2][r_l][c_l] + pfx[l][g2];
                float cn = sigmf(gv[1]) * cst[l] + sigmf(gv[0]) * tanhf(gv[2]);
                float hn = sigmf(gv[3]) * tanhf(cn);
                cst[l] = cn;
                if (!isW)
                    __builtin_nontemporal_store(hn, &enc_pad[(size_t)s * 65536 + row * 1024 + col]);
                write_frag3_nt(hout, 4, row, col, hn);
                if (isW) {
                    if (s == 79) {
                        __builtin_nontemporal_store(hn, &h_fp32[row * 1024 + col]);
                        __builtin_nontemporal_store(cn, &cglobD[row * 1024 + col]);
                    } else {
#pragma unroll
                        for (int g2 = 0; g2 < 4; ++g2)
                            pfx[l][g2] = Xwarm[((size_t)(s + 1) * 64 + row) * 4096 + g2 * 1024 + col];
                    }
                }
            }
            __syncthreads();
        }
        tree_barrier(bar, (lb >> 5), 4, 32);
    }
}

// ---------------------------------------------------------------------------
// k4: attention-decode, s=80..159. 256 blocks x 512. 2 barriers/step.
// Phase B role: rp=bid&1 (rows rp*32..+32, XCD-shared), u=bid>>1 (32 gate-cols),
// wreg[48]=192 VGPR -- requires launch_bounds(512,1)+waves_per_eu(1,2) (no spill;
// LDS 117KB already caps at 1 block/CU). Phase C' role (b=bid>>2, jc=bid&3):
// redundant full-row gates + local full logits (R14-proven).
// ---------------------------------------------------------------------------
__launch_bounds__(512, 1)
__attribute__((amdgpu_waves_per_eu(1, 2)))
__global__ void coop_dec80(const unsigned short* __restrict__ WihcF,
                           const unsigned short* __restrict__ WhhF,
                           const float* __restrict__ W1,       // [80][2048]
                           const float* __restrict__ EW2,      // [80][64][1024]
                           const float* __restrict__ S_g,
                           const float* __restrict__ ctxS,
                           const float* __restrict__ S_log,
                           const float* __restrict__ enc_pad,
                           const float* __restrict__ prelu_w,
                           const float* __restrict__ h_fp32,
                           const float* __restrict__ cglobD,
                           unsigned short* __restrict__ hfrag,  // 2 bufs (step 80 reads buf0)
                           unsigned short* __restrict__ ctxfrag,
                           float* __restrict__ h_all,
                           float* __restrict__ gsum,            // [4][64][1024]
                           unsigned* __restrict__ bar)
{
    __shared__ float EW2T[80 * 256];
    __shared__ float gred[8][1024];
    __shared__ float hfull[1024];
    __shared__ float wsm[80];
    __shared__ float rbuf[128];
    const int bid = blockIdx.x, tid = threadIdx.x;
    const int w = tid >> 6, lane = tid & 63;
    const int rp = bid & 1, u = bid >> 1;      // Phase B role (rp fixed per XCD)
    const int kq = w;
    const int b = bid >> 2, jc = bid & 3;      // Phase A'/C' role
    const float pw = prelu_w[0];

    // ---- weight slice: 2 coltiles x 8 kf x 3 planes = 48 short8v = 192 VGPR ----
    const unsigned short* Wsrc = (kq < 4) ? WihcF : WhhF;
    const int kfbase = (kq & 3) * 8;
    short8v wreg[48];
#pragma unroll
    for (int ct = 0; ct < 2; ++ct) {
        const int wbase2 = u * 2 + ct;
#pragma unroll
        for (int i = 0; i < 8; ++i) {
#pragma unroll
            for (int p = 0; p < 3; ++p)
                wreg[(ct * 8 + i) * 3 + p] =
                    *(const short8v*)&Wsrc[((size_t)(p * 256 + wbase2) * 32 + kfbase + i) * 512 + lane * 8];
        }
    }

    // ---- redundant full-row c-state: 2 cols/thread ----
    float c2[2];
    c2[0] = cglobD[b * 1024 + tid * 2];
    c2[1] = cglobD[b * 1024 + tid * 2 + 1];

    for (int i = tid; i < 80 * 256; i += 512) {
        int ss = i >> 8, j = i & 255;
        EW2T[i] = EW2[((size_t)ss * 64 + b) * 1024 + jc * 256 + j];
    }

    // ---- prologue: attention for t=0 from h_fp32 ----
    for (int i = tid; i < 1024; i += 512) hfull[i] = h_fp32[b * 1024 + i];
    __syncthreads();
    {
#pragma unroll
        for (int i = 0; i < 10; ++i) {
            int sx = w * 10 + i;
            float p = 0.f;
#pragma unroll
            for (int q = 0; q < 16; ++q)
                p = fmaf(hfull[lane + q * 64], W1[(size_t)sx * 2048 + lane + q * 64], p);
#pragma unroll
            for (int off = 32; off; off >>= 1) p += __shfl_down(p, off, 64);
            if (lane == 0) wsm[sx] = p + S_log[(size_t)b * 80 + sx];
        }
        __syncthreads();
        float v = (tid < 80) ? wsm[tid] : -3.4e38f;
        if (tid < 128) rbuf[tid] = v;
        __syncthreads();
        for (int off = 64; off >= 1; off >>= 1) {
            if (tid < off) rbuf[tid] = fmaxf(rbuf[tid], rbuf[tid + off]);
            __syncthreads();
        }
        float mx = rbuf[0];
        __syncthreads();
        float e = (tid < 80) ? __expf(wsm[tid] - mx) : 0.f;
        if (tid < 128) rbuf[tid] = e;
        __syncthreads();
        for (int off = 64; off >= 1; off >>= 1) {
            if (tid < off) rbuf[tid] += rbuf[tid + off];
            __syncthreads();
        }
        float inv = 1.f / rbuf[0];
        __syncthreads();
        if (tid < 80) wsm[tid] = e * inv;
        __syncthreads();
        if (tid < 256) {
            float f = 0.f;
#pragma unroll 8
            for (int ss = 0; ss < 80; ++ss)
                f = fmaf(wsm[ss], EW2T[ss * 256 + tid], f);
            int col = jc * 256 + tid;
            float val = f + ctxS[(size_t)b * 1024 + col];
            val = (val >= 0.f) ? val : pw * val;
            val += enc_pad[(size_t)b * 1024 + col];
            write_frag3_nt(ctxfrag, 4, b, col, val);
        }
    }
    tree_barrier(bar, bid >> 5, 8, 32);

    for (int t = 0; t < 80; ++t) {
        const int s = 80 + t;
        unsigned short* hout = hfrag + ((s + 1) & 1) * 196608;
        const unsigned short* hf = hfrag + (s & 1) * 196608;

        // ---- prefetch Phase-C' gate-adds (2 cols/thread) ----
        float pf2[2][4];
        {
            const float* xb = S_g + ((size_t)t * 64 + b) * 4096;
#pragma unroll
            for (int e = 0; e < 2; ++e) {
                int col = tid * 2 + e;
#pragma unroll
                for (int g2 = 0; g2 < 4; ++g2) pf2[e][g2] = xb[g2 * 1024 + col];
            }
        }

        // ---- Phase B: gate GEMM partials (rows rp*32..+32, 32 gate-cols) ----
        {
            f32x4 acc[2][2];
#pragma unroll
            for (int rgl = 0; rgl < 2; ++rgl)
#pragma unroll
                for (int ct = 0; ct < 2; ++ct) acc[rgl][ct] = (f32x4){0.f,0.f,0.f,0.f};
            const unsigned short* asrc = (kq < 4) ? ctxfrag : hf;
#pragma unroll
            for (int i = 0; i < 8; ++i) {
                int kfl = kfbase + i;
#pragma unroll
                for (int rgl = 0; rgl < 2; ++rgl) {
                    const int rg = rp * 2 + rgl;
                    const unsigned short* ab = asrc + ((size_t)rg * 32 + kfl) * 512 + lane * 8;
                    short8v a0 = *(const short8v*)&ab[0];
                    short8v a1 = *(const short8v*)&ab[65536];
                    short8v a2 = *(const short8v*)&ab[131072];
#pragma unroll
                    for (int ct = 0; ct < 2; ++ct) {
                        short8v b0 = wreg[(ct * 8 + i) * 3 + 0];
                        short8v b1 = wreg[(ct * 8 + i) * 3 + 1];
                        short8v b2 = wreg[(ct * 8 + i) * 3 + 2];
                        MFMA_(acc[rgl][ct], a0, b0); MFMA_(acc[rgl][ct], a0, b1);
                        MFMA_(acc[rgl][ct], a1, b0); MFMA_(acc[rgl][ct], a1, b1);
                        MFMA_(acc[rgl][ct], a0, b2); MFMA_(acc[rgl][ct], a2, b0);
                    }
                }
            }
#pragma unroll
            for (int rgl = 0; rgl < 2; ++rgl)
#pragma unroll
                for (int ct = 0; ct < 2; ++ct)
#pragma unroll
                    for (int r = 0; r < 4; ++r)
                        gred[w][(rgl * 2 + ct) * 256 + lane * 4 + r] = acc[rgl][ct][r];
            __syncthreads();
#pragma unroll
            for (int e2 = 0; e2 < 2; ++e2) {
                int slot = tid * 2 + e2;
                int t4 = slot >> 8, l = (slot >> 2) & 63, r = slot & 3;
                float sum = 0.f;
#pragma unroll
                for (int w2 = 0; w2 < 8; ++w2) sum += gred[w2][slot];
                int rgl = t4 >> 1, ct = t4 & 1;
                int row = rp * 32 + rgl * 16 + (l >> 4) * 4 + r;
                int fr = (u * 2 + ct) * 16 + (l & 15);     // gate-col in 0..4095
                __builtin_nontemporal_store(sum,
                    &gsum[((size_t)(fr >> 10) * 64 + row) * 1024 + (fr & 1023)]);
            }
        }
        tree_barrier(bar, bid >> 5, 8, 32);

        // ---- Phase C': full-row gates + h write + next-step attention ----
        {
            float hv[2];
#pragma unroll
            for (int e = 0; e < 2; ++e) {
                int col = tid * 2 + e;
                float gv[4];
#pragma unroll
                for (int g2 = 0; g2 < 4; ++g2)
                    gv[g2] = gsum[((size_t)g2 * 64 + b) * 1024 + col] + pf2[e][g2];
                float cn = sigmf(gv[1]) * c2[e] + sigmf(gv[0]) * tanhf(gv[2]);
                float hn = sigmf(gv[3]) * tanhf(cn);
                c2[e] = cn;
                hfull[col] = hn;
                hv[e] = hn;
            }
            __syncthreads();
            // write h_all + hfrag for own jc slice only
            if (tid >= jc * 128 && tid < (jc + 1) * 128) {
#pragma unroll
                for (int e = 0; e < 2; ++e) {
                    int col = tid * 2 + e;
                    __builtin_nontemporal_store(hv[e], &h_all[((size_t)t * 64 + b) * 1024 + col]);
                    write_frag3_nt(hout, 4, b, col, hv[e]);
                }
            }
            // attention for t+1 (local full logits from hfull)
            if (t < 79) {
#pragma unroll
                for (int i = 0; i < 10; ++i) {
                    int sx = w * 10 + i;
                    float p = 0.f;
#pragma unroll
                    for (int q = 0; q < 16; ++q)
                        p = fmaf(hfull[lane + q * 64], W1[(size_t)sx * 2048 + lane + q * 64], p);
#pragma unroll
                    for (int off = 32; off; off >>= 1) p += __shfl_down(p, off, 64);
                    if (lane == 0) wsm[sx] = p + S_log[((size_t)(t + 1) * 64 + b) * 80 + sx];
                }
                __syncthreads();
                float v = (tid < 80) ? wsm[tid] : -3.4e38f;
                if (tid < 128) rbuf[tid] = v;
                __syncthreads();
                for (int off = 64; off >= 1; off >>= 1) {
                    if (tid < off) rbuf[tid] = fmaxf(rbuf[tid], rbuf[tid + off]);
                    __syncthreads();
                }
                float mx = rbuf[0];
                __syncthreads();
                float e = (tid < 80) ? __expf(wsm[tid] - mx) : 0.f;
                if (tid < 128) rbuf[tid] = e;
                __syncthreads();
                for (int off = 64; off >= 1; off >>= 1) {
                    if (tid < off) rbuf[tid] += rbuf[tid + off];
                    __syncthreads();
                }
                float inv = 1.f / rbuf[0];
                __syncthreads();
                if (tid < 80) wsm[tid] = e * inv;
                __syncthreads();
                if (tid < 256) {
                    float f = 0.f;
#pragma unroll 8
                    for (int ss = 0; ss < 80; ++ss)
                        f = fmaf(wsm[ss], EW2T[ss * 256 + tid], f);
                    int col = jc * 256 + tid;
                    float val = f + ctxS[((size_t)(t + 1) * 64 + b) * 1024 + col];
                    val = (val >= 0.f) ? val : pw * val;
                    val += enc_pad[((size_t)(t + 1) * 64 + b) * 1024 + col];
                    write_frag3_nt(ctxfrag, 4, b, col, val);
                }
            }
        }
        tree_barrier(bar, bid >> 5, 8, 32);
    }
}

// ---------------------------------------------------------------------------
extern "C" void kernel_launch(void* const* d_in, const int* in_sizes, int n_in,
                              void* d_out, int out_size, void* d_ws, size_t ws_size,
                              hipStream_t stream)
{
    (void)in_sizes; (void)n_in; (void)out_size; (void)ws_size;

    const float* input_data     = (const float*)d_in[0];
    const float* correct_answer = (const float*)d_in[1];
    const float* enc_W_ih = (const float*)d_in[2];
    const float* enc_W_hh = (const float*)d_in[3];
    const float* enc_b_ih = (const float*)d_in[4];
    const float* enc_b_hh = (const float*)d_in[5];
    const float* dec_W_ih = (const float*)d_in[6];
    const float* dec_W_hh = (const float*)d_in[7];
    const float* dec_b_ih = (const float*)d_in[8];
    const float* dec_b_hh = (const float*)d_in[9];
    const float* in_emb_W = (const float*)d_in[10];
    const float* in_emb_b = (const float*)d_in[11];
    const float* out_emb_W = (const float*)d_in[12];
    const float* out_emb_b = (const float*)d_in[13];
    const float* att_W1 = (const float*)d_in[14];
    const float* att_b1 = (const float*)d_in[15];
    const float* att_W2 = (const float*)d_in[16];
    const float* att_b2 = (const float*)d_in[17];
    const float* prelu_w = (const float*)d_in[18];

    float* out = (float*)d_out;
    char* ws = (char*)d_ws;

    // ---- d_out scratch (all reads precede final vocab GEMM) ----
    float* Xbig    = out;
    float* S_g     = out + 20971520;
    float* ctxS    = out + 41943040;
    float* S_log   = out + 47185920;
    float* samples = out + 47595520;
    float* EW2     = out + 52838400;
    unsigned short* WencF = (unsigned short*)(out + 58081280);
    unsigned short* WhhDF = (unsigned short*)(out + 64372736);
    unsigned short* WihcF = (unsigned short*)(out + 70664192);

    // ---- d_ws map ----
    size_t off = 0;
    auto alloc = [&](size_t nfloats) { float* p = (float*)(ws + off); off += nfloats * 4; return p; };
    float* enc_seq = alloc(80 * 64 * 1024);
    float* enc_pad = alloc(80 * 64 * 1024);
    float* h_all   = alloc(80 * 64 * 1024);
    float* benc    = alloc(4096);
    float* bdec    = alloc(4096);
    float* zb      = alloc(1024);
    float* hfragE_f = alloc(196608);
    float* hfragD_f = alloc(196608);
    float* ctxfrag_f= alloc(98304);
    float* gsum     = alloc(262144);
    float* cglobE   = alloc(65536);
    float* cglobD   = alloc(65536);
    float* h_fp32   = alloc(65536);
    float* bar_f    = alloc(2048);
    unsigned short* hfragE  = (unsigned short*)hfragE_f;
    unsigned short* hfragD  = (unsigned short*)hfragD_f;
    unsigned short* ctxfrag = (unsigned short*)ctxfrag_f;
    unsigned* barE1 = (unsigned*)bar_f;
    unsigned* barPE = ((unsigned*)bar_f) + 512;
    unsigned* barPW = ((unsigned*)bar_f) + 1024;
    unsigned* barD  = ((unsigned*)bar_f) + 1536;

    auto big3 = [&](const float* A, int lda, const float* W, int ldw,
                    float* C, int ldc, const float* bias, int M, int N, int K) {
        dim3 g((N + 127) / 128, (M + 127) / 128);
        hipLaunchKernelGGL((gemm_mfma_split<3>), g, dim3(256), 0, stream,
                           A, lda, W, ldw, C, ldc, bias, M, N, K);
    };

    // ---- setup ----
    hipLaunchKernelGGL(vec_add2, dim3(16), dim3(256), 0, stream, enc_b_ih, enc_b_hh, benc, 4096);
    hipLaunchKernelGGL(vec_add2, dim3(16), dim3(256), 0, stream, dec_b_ih, dec_b_hh, bdec, 4096);
    hipLaunchKernelGGL(zero_f, dim3(4), dim3(256), 0, stream, zb, 1024);
    hipLaunchKernelGGL(zero_f, dim3(768), dim3(256), 0, stream, hfragE_f, 196608);
    hipLaunchKernelGGL(zero_f, dim3(768), dim3(256), 0, stream, hfragD_f, 196608);
    hipLaunchKernelGGL(zero_f, dim3(8), dim3(256), 0, stream, bar_f, 2048);

    // ---- weight frag rearranges ----
    hipLaunchKernelGGL(rearr_frag, dim3(2048), dim3(256), 0, stream, enc_W_hh, 1024, 0, WencF, 4096, 1024);
    hipLaunchKernelGGL(rearr_frag, dim3(2048), dim3(256), 0, stream, dec_W_hh, 1024, 0, WhhDF, 4096, 1024);
    hipLaunchKernelGGL(rearr_frag, dim3(2048), dim3(256), 0, stream, dec_W_ih, 2048, 1024, WihcF, 4096, 1024);

    // ---- batched big GEMMs (NS=3) ----
    big3(input_data, 4096, enc_W_ih, 4096, Xbig, 4096, benc, 5120, 4096, 4096);
    hipLaunchKernelGGL(sample0_fill, dim3(256), dim3(256), 0, stream, in_emb_W, in_emb_b, samples);
    big3(correct_answer + (size_t)64 * 20000, 20000, in_emb_W, 20000,
         samples + 65536, 1024, in_emb_b, 5056, 1024, 20000);
    big3(samples, 1024, dec_W_ih, 2048, S_g, 4096, bdec, 5120, 4096, 1024);
    big3(samples, 1024, att_W2, 2048, ctxS, 1024, att_b2, 5120, 1024, 1024);
    big3(samples, 1024, att_W1 + 1024, 2048, S_log, 80, att_b1, 5120, 80, 1024);

    // ---- k1: encoder real (80 steps) ----
    hipLaunchKernelGGL(coop_enc80, dim3(256), dim3(512), 0, stream,
                       WencF, Xbig, hfragE, enc_seq, cglobE, barE1);

    // ---- Xwarm + EW2 projections (need enc_seq) ----
    big3(enc_seq, 1024, dec_W_ih, 2048, Xbig, 4096, bdec, 5120, 4096, 1024);
    big3(enc_seq, 1024, att_W2 + 1024, 2048, EW2, 1024, zb, 5120, 1024, 1024);

    // ---- k3: enc-pad || dec warm-up (80 steps, overlapped) ----
    hipLaunchKernelGGL(coop_padwarm, dim3(256), dim3(512), 0, stream,
                       WencF, WhhDF, benc, Xbig, cglobE,
                       hfragE, hfragD, enc_pad, cglobD, h_fp32, barPE, barPW);

    // ---- k4: attention decode (80 steps, 2 barriers/step) ----
    hipLaunchKernelGGL(coop_dec80, dim3(256), dim3(512), 0, stream,
                       WihcF, WhhDF, att_W1, EW2, S_g, ctxS, S_log,
                       enc_pad, prelu_w, h_fp32, cglobD,
                       hfragD, ctxfrag, h_all, gsum, barD);

    // ---- final vocab projection (NS=1, output-facing) ----
    {
        dim3 g((20000 + 127) / 128, (5120 + 127) / 128);
        hipLaunchKernelGGL((gemm_mfma_split<1>), g, dim3(256), 0, stream,
                           h_all, 1024, out_emb_W, 1024, out, 20000, out_emb_b, 5120, 20000, 1024);
    }
}

// Round 16
// 13824.162 us; speedup vs baseline: 1.1869x; 1.1869x over previous
//
#include <hip/hip_runtime.h>
#include <cstddef>
#include <cstdint>

typedef __attribute__((ext_vector_type(8))) short short8v;
typedef __attribute__((ext_vector_type(4))) float f32x4;

__device__ __forceinline__ float sigmf(float x) { return 1.0f / (1.0f + __expf(-x)); }

__device__ __forceinline__ unsigned short bf16_rn(float x) {
    union { float f; unsigned u; } v; v.f = x;
    unsigned r = v.u + 0x7FFF + ((v.u >> 16) & 1);
    return (unsigned short)(r >> 16);
}
__device__ __forceinline__ float bf16_to_f(unsigned short h) {
    union { unsigned u; float f; } v; v.u = ((unsigned)h) << 16; return v.f;
}
__device__ __forceinline__ unsigned long long pack4(unsigned short a, unsigned short b,
                                                    unsigned short c, unsigned short d) {
    return (unsigned long long)a | ((unsigned long long)b << 16)
         | ((unsigned long long)c << 32) | ((unsigned long long)d << 48);
}

#define MFMA_(d, va, vb) d = __builtin_amdgcn_mfma_f32_16x16x32_bf16(va, vb, d, 0, 0, 0)

#define AT_LD(p)        __hip_atomic_load((p), __ATOMIC_RELAXED, __HIP_MEMORY_SCOPE_AGENT)
#define AT_ST(p, v)     __hip_atomic_store((p), (v), __ATOMIC_RELAXED, __HIP_MEMORY_SCOPE_AGENT)
#define AT_ST_REL(p, v) __hip_atomic_store((p), (v), __ATOMIC_RELEASE, __HIP_MEMORY_SCOPE_AGENT)
#define AT_ADD(p, v)    __hip_atomic_fetch_add((p), (v), __ATOMIC_RELAXED, __HIP_MEMORY_SCOPE_AGENT)

// ---------------------------------------------------------------------------
// Fragment layout (A and W): F[p][rgw][kf][l][e]; rgw=r>>4, kf=k>>5,
// l=((k>>3)&3)*16+(r&15), e=k&7. Per-(p,rgw) chunk = 32*64*8 = 16384 shorts.
// ---------------------------------------------------------------------------
__device__ __forceinline__ void write_frag3_nt(unsigned short* __restrict__ dst, int NRGW,
                                               int r, int k, float x)
{
    unsigned short hi = bf16_rn(x); float r1 = x - bf16_to_f(hi);
    unsigned short md = bf16_rn(r1);
    unsigned short lo = bf16_rn(r1 - bf16_to_f(md));
    int base = (((r >> 4) * 32 + (k >> 5)) * 64 + ((k >> 3) & 3) * 16 + (r & 15)) * 8 + (k & 7);
    int ps = NRGW * 16384;
    __builtin_nontemporal_store(hi, &dst[base]);
    __builtin_nontemporal_store(md, &dst[ps + base]);
    __builtin_nontemporal_store(lo, &dst[2 * ps + base]);
}

__launch_bounds__(256)
__global__ void rearr_frag(const float* __restrict__ src, int ld, int c0,
                           unsigned short* __restrict__ dst, int R, int K)
{
    int idx = blockIdx.x * 256 + threadIdx.x;
    int kpr = K >> 3;
    if (idx >= R * kpr) return;
    int r = idx / kpr, k = (idx % kpr) * 8;
    int NRGW = R >> 4;
    const float* s = src + (size_t)r * ld + c0 + k;
    float4 v0 = *(const float4*)s, v1 = *(const float4*)(s + 4);
    float xs[8] = {v0.x, v0.y, v0.z, v0.w, v1.x, v1.y, v1.z, v1.w};
    unsigned short hi[8], md[8], lo[8];
#pragma unroll
    for (int e = 0; e < 8; ++e) {
        hi[e] = bf16_rn(xs[e]); float r1 = xs[e] - bf16_to_f(hi[e]);
        md[e] = bf16_rn(r1);
        lo[e] = bf16_rn(r1 - bf16_to_f(md[e]));
    }
    int base = (((r >> 4) * 32 + (k >> 5)) * 64 + ((k >> 3) & 3) * 16 + (r & 15)) * 8;
    size_t ps = (size_t)NRGW * 16384;
    *(unsigned long long*)&dst[base]          = pack4(hi[0], hi[1], hi[2], hi[3]);
    *(unsigned long long*)&dst[base + 4]      = pack4(hi[4], hi[5], hi[6], hi[7]);
    *(unsigned long long*)&dst[ps + base]     = pack4(md[0], md[1], md[2], md[3]);
    *(unsigned long long*)&dst[ps + base + 4] = pack4(md[4], md[5], md[6], md[7]);
    *(unsigned long long*)&dst[2*ps + base]     = pack4(lo[0], lo[1], lo[2], lo[3]);
    *(unsigned long long*)&dst[2*ps + base + 4] = pack4(lo[4], lo[5], lo[6], lo[7]);
}

// ---------------------------------------------------------------------------
// Two-level tree barrier; gidx = this block's group, ng groups, bpg blocks ea.
// ---------------------------------------------------------------------------
__device__ __forceinline__ void tree_barrier(unsigned* bar, int gidx, int ng, int bpg)
{
    __syncthreads();
    if (threadIdx.x == 0) {
        unsigned* gcnt = bar + gidx * 32;
        unsigned* ggen = bar + gidx * 32 + 1;
        unsigned* rcnt = bar + ng * 32;
        unsigned* rgen = bar + ng * 32 + 1;
        __threadfence();   // release
        unsigned mygen = AT_LD(ggen);
        unsigned prev = AT_ADD(gcnt, 1u);
        if (prev == (unsigned)(bpg - 1)) {
            AT_ST(gcnt, 0u);
            unsigned rg = AT_LD(rgen);
            unsigned rprev = AT_ADD(rcnt, 1u);
            if (rprev == (unsigned)(ng - 1)) {
                AT_ST(rcnt, 0u);
                AT_ST_REL(rgen, rg + 1u);
            } else {
                while (AT_LD(rgen) == rg) __builtin_amdgcn_s_sleep(1);
            }
            AT_ST_REL(ggen, mygen + 1u);
        } else {
            while (AT_LD(ggen) == mygen) __builtin_amdgcn_s_sleep(1);
        }
        __threadfence();   // acquire
    }
    __syncthreads();
}

// ---------------------------------------------------------------------------
// Batched fp32 GEMM via bf16-split MFMA (validated R3): C = A@W^T + bias.
// ---------------------------------------------------------------------------
template <int NS>
__launch_bounds__(256, 2)
__global__ void gemm_mfma_split(const float* __restrict__ A, int lda,
                                const float* __restrict__ W, int ldw,
                                float* __restrict__ C, int ldc,
                                const float* __restrict__ bias,
                                int M, int N, int K)
{
    __shared__ unsigned short Abf[NS][128][40];
    __shared__ unsigned short Bbf[NS][128][40];
    const int tid = threadIdx.x;
    const int m0 = blockIdx.y * 128, n0 = blockIdx.x * 128;
    const int wave = tid >> 6, lane = tid & 63;
    const int wr = wave >> 1, wc = wave & 1;
    const int lr = lane & 15, lk = (lane >> 4) * 8;

    f32x4 acc[4][4];
#pragma unroll
    for (int i = 0; i < 4; ++i)
#pragma unroll
        for (int j = 0; j < 4; ++j) acc[i][j] = (f32x4){0.f, 0.f, 0.f, 0.f};

    const int arow = tid >> 1;
    const int akh  = (tid & 1) * 16;
    int gr = m0 + arow; if (gr > M - 1) gr = M - 1;
    int gn = n0 + arow; if (gn > N - 1) gn = N - 1;
    const float* aptr = A + (size_t)gr * lda + akh;
    const float* wptr = W + (size_t)gn * ldw + akh;

    for (int k0 = 0; k0 < K; k0 += 32) {
#pragma unroll
        for (int q = 0; q < 4; ++q) {
            float4 v = *(const float4*)(aptr + k0 + q * 4);
            float xs[4] = {v.x, v.y, v.z, v.w};
            unsigned short h[4], hm[4], hl[4];
#pragma unroll
            for (int e = 0; e < 4; ++e) {
                h[e] = bf16_rn(xs[e]);
                if (NS == 3) {
                    float r1 = xs[e] - bf16_to_f(h[e]);
                    hm[e] = bf16_rn(r1);
                    hl[e] = bf16_rn(r1 - bf16_to_f(hm[e]));
                }
            }
            *(unsigned long long*)&Abf[0][arow][akh + q * 4] = pack4(h[0], h[1], h[2], h[3]);
            if (NS == 3) {
                *(unsigned long long*)&Abf[1][arow][akh + q * 4] = pack4(hm[0], hm[1], hm[2], hm[3]);
                *(unsigned long long*)&Abf[2][arow][akh + q * 4] = pack4(hl[0], hl[1], hl[2], hl[3]);
            }
        }
#pragma unroll
        for (int q = 0; q < 4; ++q) {
            float4 v = *(const float4*)(wptr + k0 + q * 4);
            float xs[4] = {v.x, v.y, v.z, v.w};
            unsigned short h[4], hm[4], hl[4];
#pragma unroll
            for (int e = 0; e < 4; ++e) {
                h[e] = bf16_rn(xs[e]);
                if (NS == 3) {
                    float r1 = xs[e] - bf16_to_f(h[e]);
                    hm[e] = bf16_rn(r1);
                    hl[e] = bf16_rn(r1 - bf16_to_f(hm[e]));
                }
            }
            *(unsigned long long*)&Bbf[0][arow][akh + q * 4] = pack4(h[0], h[1], h[2], h[3]);
            if (NS == 3) {
                *(unsigned long long*)&Bbf[1][arow][akh + q * 4] = pack4(hm[0], hm[1], hm[2], hm[3]);
                *(unsigned long long*)&Bbf[2][arow][akh + q * 4] = pack4(hl[0], hl[1], hl[2], hl[3]);
            }
        }
        __syncthreads();

        short8v a[NS][4], b[4];
#pragma unroll
        for (int p = 0; p < NS; ++p)
#pragma unroll
            for (int i = 0; i < 4; ++i)
                a[p][i] = *(const short8v*)&Abf[p][wr * 64 + i * 16 + lr][lk];
#pragma unroll
        for (int q = 0; q < NS; ++q) {
#pragma unroll
            for (int j = 0; j < 4; ++j)
                b[j] = *(const short8v*)&Bbf[q][wc * 64 + j * 16 + lr][lk];
            const int pmax = (NS == 1) ? 1 : (3 - q);
#pragma unroll
            for (int p = 0; p < 3; ++p) {
                if (p >= pmax) break;
#pragma unroll
                for (int i = 0; i < 4; ++i)
#pragma unroll
                    for (int j = 0; j < 4; ++j)
                        acc[i][j] = __builtin_amdgcn_mfma_f32_16x16x32_bf16(
                            a[p][i], b[j], acc[i][j], 0, 0, 0);
            }
        }
        __syncthreads();
    }

    const int crow = (lane >> 4) * 4;
#pragma unroll
    for (int i = 0; i < 4; ++i) {
        int mbase = m0 + wr * 64 + i * 16 + crow;
#pragma unroll
        for (int j = 0; j < 4; ++j) {
            int n = n0 + wc * 64 + j * 16 + lr;
            if (n < N) {
                float bv = bias[n];
#pragma unroll
                for (int r = 0; r < 4; ++r) {
                    int m = mbase + r;
                    if (m < M) C[(size_t)m * ldc + n] = acc[i][j][r] + bv;
                }
            }
        }
    }
}

__launch_bounds__(256)
__global__ void zero_f(float* __restrict__ p, int n)
{
    int i = blockIdx.x * 256 + threadIdx.x;
    if (i < n) p[i] = 0.f;
}

__launch_bounds__(256)
__global__ void vec_add2(const float* __restrict__ a, const float* __restrict__ b,
                         float* __restrict__ o, int n)
{
    int i = blockIdx.x * 256 + threadIdx.x;
    if (i < n) o[i] = a[i] + b[i];
}

__launch_bounds__(256)
__global__ void sample0_fill(const float* __restrict__ emW, const float* __restrict__ emb,
                             float* __restrict__ samples)
{
    int idx = blockIdx.x * 256 + threadIdx.x; // 65536
    int d = idx & 1023;
    samples[idx] = emW[(size_t)d * 20000 + 19998] + emb[d];
}

// stage one rg-chunk (96KB) of a 64-row frag buffer into LDS
__device__ __forceinline__ void stage_A(unsigned short* __restrict__ LDSA,
                                        const unsigned short* __restrict__ src,
                                        int rg, int tid)
{
#pragma unroll
    for (int p = 0; p < 3; ++p) {
        const unsigned short* sp = src + (size_t)(p * 4 + rg) * 16384;
        unsigned short* dp = LDSA + p * 16384;
#pragma unroll
        for (int it = 0; it < 4; ++it) {
            int idx = tid + it * 512;
            *(short8v*)&dp[idx * 8] = *(const short8v*)&sp[idx * 8];
        }
    }
}

// 16-kf MFMA block from LDSA rg-chunk vs wreg (encoder-style, in-block gates)
__device__ __forceinline__ f32x4 mfma16(const unsigned short* __restrict__ LDSA,
                                        const short8v* __restrict__ wreg,
                                        int kh, int lane)
{
    f32x4 acc0 = (f32x4){0.f,0.f,0.f,0.f}, acc1 = acc0;
#pragma unroll
    for (int i = 0; i < 16; ++i) {
        int kf = kh * 16 + i;
        short8v a0 = *(const short8v*)&LDSA[(kf * 64 + lane) * 8];
        short8v a1 = *(const short8v*)&LDSA[16384 + (kf * 64 + lane) * 8];
        short8v a2 = *(const short8v*)&LDSA[32768 + (kf * 64 + lane) * 8];
        short8v b0 = wreg[i * 3 + 0], b1 = wreg[i * 3 + 1], b2 = wreg[i * 3 + 2];
        f32x4& A = (i & 1) ? acc1 : acc0;
        MFMA_(A, a0, b0); MFMA_(A, a0, b1); MFMA_(A, a1, b0);
        MFMA_(A, a1, b1); MFMA_(A, a0, b2); MFMA_(A, a2, b0);
    }
    return acc0 + acc1;
}

// ---------------------------------------------------------------------------
// k1: encoder real steps 0..79. 256 blocks x 512. 1 barrier/step.
// XCD-local rg: rg = bid&3 (bid%8 = XCD => bid&3 constant per XCD).
// ---------------------------------------------------------------------------
__launch_bounds__(512, 1)
__attribute__((amdgpu_waves_per_eu(1, 2)))
__global__ void coop_enc80(const unsigned short* __restrict__ WencF,
                           const float* __restrict__ Xbig,
                           unsigned short* __restrict__ hfrag,   // 2 bufs x 196608
                           float* __restrict__ enc_seq,
                           float* __restrict__ cglobE,
                           unsigned* __restrict__ bar)
{
    __shared__ unsigned short LDSA[3 * 16384];
    __shared__ float gbuf[8][16][16];
    const int bid = blockIdx.x, tid = threadIdx.x;
    const int w = tid >> 6, lane = tid & 63;
    const int g = w & 3, kh = w >> 2;
    const int rg = bid & 3, cg = bid >> 2;
    const int wbase = g * 64 + cg;
    const int r_l = (tid & 255) >> 4, c_l = tid & 15;
    const int row = rg * 16 + r_l, col = cg * 16 + c_l;
    float cstate = 0.f;

    short8v wreg[48];
#pragma unroll
    for (int i = 0; i < 16; ++i) {
        int kf = kh * 16 + i;
#pragma unroll
        for (int p = 0; p < 3; ++p)
            wreg[i * 3 + p] = *(const short8v*)&WencF[((size_t)(p * 256 + wbase) * 32 + kf) * 512 + lane * 8];
    }

    float pf[4];
    if (tid < 256) {
#pragma unroll
        for (int g2 = 0; g2 < 4; ++g2)
            pf[g2] = Xbig[(size_t)row * 4096 + g2 * 1024 + col];
    }

    for (int s = 0; s < 80; ++s) {
        const unsigned short* hf = hfrag + (s & 1) * 196608;
        stage_A(LDSA, hf, rg, tid);
        __syncthreads();
        f32x4 acc = mfma16(LDSA, wreg, kh, lane);
#pragma unroll
        for (int r = 0; r < 4; ++r)
            gbuf[w][(lane >> 4) * 4 + r][lane & 15] = acc[r];
        __syncthreads();

        if (tid < 256) {
            float gv[4];
#pragma unroll
            for (int g2 = 0; g2 < 4; ++g2)
                gv[g2] = gbuf[g2][r_l][c_l] + gbuf[4 + g2][r_l][c_l] + pf[g2];
            float cn = sigmf(gv[1]) * cstate + sigmf(gv[0]) * tanhf(gv[2]);
            float hn = sigmf(gv[3]) * tanhf(cn);
            cstate = cn;
            __builtin_nontemporal_store(hn, &enc_seq[(size_t)s * 65536 + row * 1024 + col]);
            write_frag3_nt(hfrag + ((s + 1) & 1) * 196608, 4, row, col, hn);
            if (s == 79) __builtin_nontemporal_store(cstate, &cglobE[row * 1024 + col]);
            else {
#pragma unroll
                for (int g2 = 0; g2 < 4; ++g2)
                    pf[g2] = Xbig[((size_t)(s + 1) * 64 + row) * 4096 + g2 * 1024 + col];
            }
        }
        tree_barrier(bar, bid >> 5, 8, 32);
    }
}

// ---------------------------------------------------------------------------
// k3: enc-pad (blocks 0..127) CONCURRENT WITH dec warm-up (blocks 128..255).
// XCD-local rg2 = lb&1 (same-XCD blocks share the rg pair).
// ---------------------------------------------------------------------------
__launch_bounds__(512, 1)
__attribute__((amdgpu_waves_per_eu(1, 2)))
__global__ void coop_padwarm(const unsigned short* __restrict__ WencF,
                             const unsigned short* __restrict__ WdecF,
                             const float* __restrict__ benc,
                             const float* __restrict__ Xwarm,
                             const float* __restrict__ cglobE,
                             unsigned short* __restrict__ hfragE,
                             unsigned short* __restrict__ hfragD,
                             float* __restrict__ enc_pad,
                             float* __restrict__ cglobD,
                             float* __restrict__ h_fp32,
                             unsigned* __restrict__ barE,
                             unsigned* __restrict__ barW)
{
    __shared__ unsigned short LDSA[3 * 16384];
    __shared__ float gbuf[8][16][16];
    const int bid = blockIdx.x, tid = threadIdx.x;
    const int w = tid >> 6, lane = tid & 63;
    const int g = w & 3, kh = w >> 2;
    const bool isW = bid >= 128;
    const int lb = bid & 127;
    const int rg2 = lb & 1, cg = lb >> 1;
    const int wbase = g * 64 + cg;
    const int r_l = (tid & 255) >> 4, c_l = tid & 15;
    const int col = cg * 16 + c_l;
    const unsigned short* Wf = isW ? WdecF : WencF;
    unsigned short* hfrag = isW ? hfragD : hfragE;
    unsigned* bar = isW ? barW : barE;

    short8v wreg[48];
#pragma unroll
    for (int i = 0; i < 16; ++i) {
        int kf = kh * 16 + i;
#pragma unroll
        for (int p = 0; p < 3; ++p)
            wreg[i * 3 + p] = *(const short8v*)&Wf[((size_t)(p * 256 + wbase) * 32 + kf) * 512 + lane * 8];
    }

    float cst[2] = {0.f, 0.f};
    float pfx[2][4];
    if (tid < 256) {
#pragma unroll
        for (int l = 0; l < 2; ++l) {
            int row = rg2 * 32 + l * 16 + r_l;
            if (!isW) cst[l] = cglobE[row * 1024 + col];
#pragma unroll
            for (int g2 = 0; g2 < 4; ++g2)
                pfx[l][g2] = isW ? Xwarm[(size_t)row * 4096 + g2 * 1024 + col]
                                 : benc[g2 * 1024 + col];
        }
    }

    for (int s = 0; s < 80; ++s) {
        const unsigned short* hf = hfrag + (s & 1) * 196608;
        unsigned short* hout = hfrag + ((s + 1) & 1) * 196608;
#pragma unroll
        for (int l = 0; l < 2; ++l) {
            const int rgi = rg2 * 2 + l;
            stage_A(LDSA, hf, rgi, tid);
            __syncthreads();
            f32x4 acc = mfma16(LDSA, wreg, kh, lane);
#pragma unroll
            for (int r = 0; r < 4; ++r)
                gbuf[w][(lane >> 4) * 4 + r][lane & 15] = acc[r];
            __syncthreads();
            if (tid < 256) {
                const int row = rgi * 16 + r_l;
                float gv[4];
#pragma unroll
                for (int g2 = 0; g2 < 4; ++g2)
                    gv[g2] = gbuf[g2][r_l][c_l] + gbuf[4 + g2][r_l][c_l] + pfx[l][g2];
                float cn = sigmf(gv[1]) * cst[l] + sigmf(gv[0]) * tanhf(gv[2]);
                float hn = sigmf(gv[3]) * tanhf(cn);
                cst[l] = cn;
                if (!isW)
                    __builtin_nontemporal_store(hn, &enc_pad[(size_t)s * 65536 + row * 1024 + col]);
                write_frag3_nt(hout, 4, row, col, hn);
                if (isW) {
                    if (s == 79) {
                        __builtin_nontemporal_store(hn, &h_fp32[row * 1024 + col]);
                        __builtin_nontemporal_store(cn, &cglobD[row * 1024 + col]);
                    } else {
#pragma unroll
                        for (int g2 = 0; g2 < 4; ++g2)
                            pfx[l][g2] = Xwarm[((size_t)(s + 1) * 64 + row) * 4096 + g2 * 1024 + col];
                    }
                }
            }
            __syncthreads();
        }
        tree_barrier(bar, (lb >> 5), 4, 32);
    }
}

// ---------------------------------------------------------------------------
// k4: attention-decode, s=80..159. 256 blocks x 512. 2 barriers/step.
// Phase B role (gg,cg), wreg[24] (96 VGPR, no spill). Phase C' role
// (b=bid>>2, jc=bid&3): redundant full-row gates + local full logits.
// Prologue does the t=0 attention from h_fp32. (R14-proven.)
// ---------------------------------------------------------------------------
__launch_bounds__(512, 2)
__global__ void coop_dec80(const unsigned short* __restrict__ WihcF,
                           const unsigned short* __restrict__ WhhF,
                           const float* __restrict__ W1,       // [80][2048]
                           const float* __restrict__ EW2,      // [80][64][1024]
                           const float* __restrict__ S_g,
                           const float* __restrict__ ctxS,
                           const float* __restrict__ S_log,
                           const float* __restrict__ enc_pad,
                           const float* __restrict__ prelu_w,
                           const float* __restrict__ h_fp32,
                           const float* __restrict__ cglobD,
                           unsigned short* __restrict__ hfrag,  // 2 bufs (step 80 reads buf0)
                           unsigned short* __restrict__ ctxfrag,
                           float* __restrict__ h_all,
                           float* __restrict__ gsum,            // [4][64][1024]
                           unsigned* __restrict__ bar)
{
    __shared__ float EW2T[80 * 256];
    __shared__ float gred[8][1024];
    __shared__ float hfull[1024];
    __shared__ float wsm[80];
    __shared__ float rbuf[128];
    const int bid = blockIdx.x, tid = threadIdx.x;
    const int w = tid >> 6, lane = tid & 63;
    const int gg = bid >> 6, cg = bid & 63;
    const int wbase = gg * 64 + cg;
    const int kq = w;
    const int b = bid >> 2, jc = bid & 3;
    const float pw = prelu_w[0];

    // ---- weight slice: 8 kf x 3 planes = 96 VGPRs ----
    const unsigned short* Wsrc = (kq < 4) ? WihcF : WhhF;
    const int kfbase = (kq & 3) * 8;
    short8v wreg[24];
#pragma unroll
    for (int i = 0; i < 8; ++i) {
#pragma unroll
        for (int p = 0; p < 3; ++p)
            wreg[i * 3 + p] = *(const short8v*)&Wsrc[((size_t)(p * 256 + wbase) * 32 + kfbase + i) * 512 + lane * 8];
    }

    // ---- redundant full-row c-state: 2 cols/thread ----
    float c2[2];
    c2[0] = cglobD[b * 1024 + tid * 2];
    c2[1] = cglobD[b * 1024 + tid * 2 + 1];

    for (int i = tid; i < 80 * 256; i += 512) {
        int ss = i >> 8, j = i & 255;
        EW2T[i] = EW2[((size_t)ss * 64 + b) * 1024 + jc * 256 + j];
    }

    // ---- prologue: attention for t=0 from h_fp32 ----
    for (int i = tid; i < 1024; i += 512) hfull[i] = h_fp32[b * 1024 + i];
    __syncthreads();
    {
#pragma unroll
        for (int i = 0; i < 10; ++i) {
            int sx = w * 10 + i;
            float p = 0.f;
#pragma unroll
            for (int q = 0; q < 16; ++q)
                p = fmaf(hfull[lane + q * 64], W1[(size_t)sx * 2048 + lane + q * 64], p);
#pragma unroll
            for (int off = 32; off; off >>= 1) p += __shfl_down(p, off, 64);
            if (lane == 0) wsm[sx] = p + S_log[(size_t)b * 80 + sx];
        }
        __syncthreads();
        float v = (tid < 80) ? wsm[tid] : -3.4e38f;
        if (tid < 128) rbuf[tid] = v;
        __syncthreads();
        for (int off = 64; off >= 1; off >>= 1) {
            if (tid < off) rbuf[tid] = fmaxf(rbuf[tid], rbuf[tid + off]);
            __syncthreads();
        }
        float mx = rbuf[0];
        __syncthreads();
        float e = (tid < 80) ? __expf(wsm[tid] - mx) : 0.f;
        if (tid < 128) rbuf[tid] = e;
        __syncthreads();
        for (int off = 64; off >= 1; off >>= 1) {
            if (tid < off) rbuf[tid] += rbuf[tid + off];
            __syncthreads();
        }
        float inv = 1.f / rbuf[0];
        __syncthreads();
        if (tid < 80) wsm[tid] = e * inv;
        __syncthreads();
        if (tid < 256) {
            float f = 0.f;
#pragma unroll 8
            for (int ss = 0; ss < 80; ++ss)
                f = fmaf(wsm[ss], EW2T[ss * 256 + tid], f);
            int col = jc * 256 + tid;
            float val = f + ctxS[(size_t)b * 1024 + col];
            val = (val >= 0.f) ? val : pw * val;
            val += enc_pad[(size_t)b * 1024 + col];
            write_frag3_nt(ctxfrag, 4, b, col, val);
        }
    }
    tree_barrier(bar, bid >> 5, 8, 32);

    for (int t = 0; t < 80; ++t) {
        const int s = 80 + t;
        unsigned short* hout = hfrag + ((s + 1) & 1) * 196608;
        const unsigned short* hf = hfrag + (s & 1) * 196608;

        // ---- prefetch Phase-C' gate-adds (2 cols/thread) ----
        float pf2[2][4];
        {
            const float* xb = S_g + ((size_t)t * 64 + b) * 4096;
#pragma unroll
            for (int e = 0; e < 2; ++e) {
                int col = tid * 2 + e;
#pragma unroll
                for (int g2 = 0; g2 < 4; ++g2) pf2[e][g2] = xb[g2 * 1024 + col];
            }
        }

        // ---- Phase B: gate GEMM partials ----
        {
            f32x4 acc[4];
#pragma unroll
            for (int rg = 0; rg < 4; ++rg) acc[rg] = (f32x4){0.f,0.f,0.f,0.f};
            const unsigned short* asrc = (kq < 4) ? ctxfrag : hf;
#pragma unroll
            for (int i = 0; i < 8; ++i) {
                int kfl = kfbase + i;
#pragma unroll
                for (int rg = 0; rg < 4; ++rg) {
                    const unsigned short* ab = asrc + ((size_t)rg * 32 + kfl) * 512 + lane * 8;
                    short8v a0 = *(const short8v*)&ab[0];
                    short8v a1 = *(const short8v*)&ab[65536];
                    short8v a2 = *(const short8v*)&ab[131072];
                    short8v b0 = wreg[i * 3 + 0], b1 = wreg[i * 3 + 1], b2 = wreg[i * 3 + 2];
                    MFMA_(acc[rg], a0, b0); MFMA_(acc[rg], a0, b1); MFMA_(acc[rg], a1, b0);
                    MFMA_(acc[rg], a1, b1); MFMA_(acc[rg], a0, b2); MFMA_(acc[rg], a2, b0);
                }
            }
#pragma unroll
            for (int rg = 0; rg < 4; ++rg)
#pragma unroll
                for (int r = 0; r < 4; ++r)
                    gred[w][rg * 256 + lane * 4 + r] = acc[rg][r];
            __syncthreads();
#pragma unroll
            for (int e2 = 0; e2 < 2; ++e2) {
                int slot = tid * 2 + e2;
                int rg = slot >> 8, l = (slot >> 2) & 63, r = slot & 3;
                float sum = 0.f;
#pragma unroll
                for (int w2 = 0; w2 < 8; ++w2) sum += gred[w2][slot];
                int row = rg * 16 + (l >> 4) * 4 + r;
                int col = cg * 16 + (l & 15);
                __builtin_nontemporal_store(sum, &gsum[((size_t)gg * 64 + row) * 1024 + col]);
            }
        }
        tree_barrier(bar, bid >> 5, 8, 32);

        // ---- Phase C': full-row gates + h write + next-step attention ----
        {
            float hv[2];
#pragma unroll
            for (int e = 0; e < 2; ++e) {
                int col = tid * 2 + e;
                float gv[4];
#pragma unroll
                for (int g2 = 0; g2 < 4; ++g2)
                    gv[g2] = gsum[((size_t)g2 * 64 + b) * 1024 + col] + pf2[e][g2];
                float cn = sigmf(gv[1]) * c2[e] + sigmf(gv[0]) * tanhf(gv[2]);
                float hn = sigmf(gv[3]) * tanhf(cn);
                c2[e] = cn;
                hfull[col] = hn;
                hv[e] = hn;
            }
            __syncthreads();
            // write h_all + hfrag for own jc slice only
            if (tid >= jc * 128 && tid < (jc + 1) * 128) {
#pragma unroll
                for (int e = 0; e < 2; ++e) {
                    int col = tid * 2 + e;
                    __builtin_nontemporal_store(hv[e], &h_all[((size_t)t * 64 + b) * 1024 + col]);
                    write_frag3_nt(hout, 4, b, col, hv[e]);
                }
            }
            // attention for t+1 (local full logits from hfull)
            if (t < 79) {
#pragma unroll
                for (int i = 0; i < 10; ++i) {
                    int sx = w * 10 + i;
                    float p = 0.f;
#pragma unroll
                    for (int q = 0; q < 16; ++q)
                        p = fmaf(hfull[lane + q * 64], W1[(size_t)sx * 2048 + lane + q * 64], p);
#pragma unroll
                    for (int off = 32; off; off >>= 1) p += __shfl_down(p, off, 64);
                    if (lane == 0) wsm[sx] = p + S_log[((size_t)(t + 1) * 64 + b) * 80 + sx];
                }
                __syncthreads();
                float v = (tid < 80) ? wsm[tid] : -3.4e38f;
                if (tid < 128) rbuf[tid] = v;
                __syncthreads();
                for (int off = 64; off >= 1; off >>= 1) {
                    if (tid < off) rbuf[tid] = fmaxf(rbuf[tid], rbuf[tid + off]);
                    __syncthreads();
                }
                float mx = rbuf[0];
                __syncthreads();
                float e = (tid < 80) ? __expf(wsm[tid] - mx) : 0.f;
                if (tid < 128) rbuf[tid] = e;
                __syncthreads();
                for (int off = 64; off >= 1; off >>= 1) {
                    if (tid < off) rbuf[tid] += rbuf[tid + off];
                    __syncthreads();
                }
                float inv = 1.f / rbuf[0];
                __syncthreads();
                if (tid < 80) wsm[tid] = e * inv;
                __syncthreads();
                if (tid < 256) {
                    float f = 0.f;
#pragma unroll 8
                    for (int ss = 0; ss < 80; ++ss)
                        f = fmaf(wsm[ss], EW2T[ss * 256 + tid], f);
                    int col = jc * 256 + tid;
                    float val = f + ctxS[((size_t)(t + 1) * 64 + b) * 1024 + col];
                    val = (val >= 0.f) ? val : pw * val;
                    val += enc_pad[((size_t)(t + 1) * 64 + b) * 1024 + col];
                    write_frag3_nt(ctxfrag, 4, b, col, val);
                }
            }
        }
        tree_barrier(bar, bid >> 5, 8, 32);
    }
}

// ---------------------------------------------------------------------------
extern "C" void kernel_launch(void* const* d_in, const int* in_sizes, int n_in,
                              void* d_out, int out_size, void* d_ws, size_t ws_size,
                              hipStream_t stream)
{
    (void)in_sizes; (void)n_in; (void)out_size; (void)ws_size;

    const float* input_data     = (const float*)d_in[0];
    const float* correct_answer = (const float*)d_in[1];
    const float* enc_W_ih = (const float*)d_in[2];
    const float* enc_W_hh = (const float*)d_in[3];
    const float* enc_b_ih = (const float*)d_in[4];
    const float* enc_b_hh = (const float*)d_in[5];
    const float* dec_W_ih = (const float*)d_in[6];
    const float* dec_W_hh = (const float*)d_in[7];
    const float* dec_b_ih = (const float*)d_in[8];
    const float* dec_b_hh = (const float*)d_in[9];
    const float* in_emb_W = (const float*)d_in[10];
    const float* in_emb_b = (const float*)d_in[11];
    const float* out_emb_W = (const float*)d_in[12];
    const float* out_emb_b = (const float*)d_in[13];
    const float* att_W1 = (const float*)d_in[14];
    const float* att_b1 = (const float*)d_in[15];
    const float* att_W2 = (const float*)d_in[16];
    const float* att_b2 = (const float*)d_in[17];
    const float* prelu_w = (const float*)d_in[18];

    float* out = (float*)d_out;
    char* ws = (char*)d_ws;

    // ---- d_out scratch (all reads precede final vocab GEMM) ----
    float* Xbig    = out;
    float* S_g     = out + 20971520;
    float* ctxS    = out + 41943040;
    float* S_log   = out + 47185920;
    float* samples = out + 47595520;
    float* EW2     = out + 52838400;
    unsigned short* WencF = (unsigned short*)(out + 58081280);
    unsigned short* WhhDF = (unsigned short*)(out + 64372736);
    unsigned short* WihcF = (unsigned short*)(out + 70664192);

    // ---- d_ws map ----
    size_t off = 0;
    auto alloc = [&](size_t nfloats) { float* p = (float*)(ws + off); off += nfloats * 4; return p; };
    float* enc_seq = alloc(80 * 64 * 1024);
    float* enc_pad = alloc(80 * 64 * 1024);
    float* h_all   = alloc(80 * 64 * 1024);
    float* benc    = alloc(4096);
    float* bdec    = alloc(4096);
    float* zb      = alloc(1024);
    float* hfragE_f = alloc(196608);
    float* hfragD_f = alloc(196608);
    float* ctxfrag_f= alloc(98304);
    float* gsum     = alloc(262144);
    float* cglobE   = alloc(65536);
    float* cglobD   = alloc(65536);
    float* h_fp32   = alloc(65536);
    float* bar_f    = alloc(2048);
    unsigned short* hfragE  = (unsigned short*)hfragE_f;
    unsigned short* hfragD  = (unsigned short*)hfragD_f;
    unsigned short* ctxfrag = (unsigned short*)ctxfrag_f;
    unsigned* barE1 = (unsigned*)bar_f;
    unsigned* barPE = ((unsigned*)bar_f) + 512;
    unsigned* barPW = ((unsigned*)bar_f) + 1024;
    unsigned* barD  = ((unsigned*)bar_f) + 1536;

    auto big3 = [&](const float* A, int lda, const float* W, int ldw,
                    float* C, int ldc, const float* bias, int M, int N, int K) {
        dim3 g((N + 127) / 128, (M + 127) / 128);
        hipLaunchKernelGGL((gemm_mfma_split<3>), g, dim3(256), 0, stream,
                           A, lda, W, ldw, C, ldc, bias, M, N, K);
    };

    // ---- setup ----
    hipLaunchKernelGGL(vec_add2, dim3(16), dim3(256), 0, stream, enc_b_ih, enc_b_hh, benc, 4096);
    hipLaunchKernelGGL(vec_add2, dim3(16), dim3(256), 0, stream, dec_b_ih, dec_b_hh, bdec, 4096);
    hipLaunchKernelGGL(zero_f, dim3(4), dim3(256), 0, stream, zb, 1024);
    hipLaunchKernelGGL(zero_f, dim3(768), dim3(256), 0, stream, hfragE_f, 196608);
    hipLaunchKernelGGL(zero_f, dim3(768), dim3(256), 0, stream, hfragD_f, 196608);
    hipLaunchKernelGGL(zero_f, dim3(8), dim3(256), 0, stream, bar_f, 2048);

    // ---- weight frag rearranges ----
    hipLaunchKernelGGL(rearr_frag, dim3(2048), dim3(256), 0, stream, enc_W_hh, 1024, 0, WencF, 4096, 1024);
    hipLaunchKernelGGL(rearr_frag, dim3(2048), dim3(256), 0, stream, dec_W_hh, 1024, 0, WhhDF, 4096, 1024);
    hipLaunchKernelGGL(rearr_frag, dim3(2048), dim3(256), 0, stream, dec_W_ih, 2048, 1024, WihcF, 4096, 1024);

    // ---- batched big GEMMs (NS=3) ----
    big3(input_data, 4096, enc_W_ih, 4096, Xbig, 4096, benc, 5120, 4096, 4096);
    hipLaunchKernelGGL(sample0_fill, dim3(256), dim3(256), 0, stream, in_emb_W, in_emb_b, samples);
    big3(correct_answer + (size_t)64 * 20000, 20000, in_emb_W, 20000,
         samples + 65536, 1024, in_emb_b, 5056, 1024, 20000);
    big3(samples, 1024, dec_W_ih, 2048, S_g, 4096, bdec, 5120, 4096, 1024);
    big3(samples, 1024, att_W2, 2048, ctxS, 1024, att_b2, 5120, 1024, 1024);
    big3(samples, 1024, att_W1 + 1024, 2048, S_log, 80, att_b1, 5120, 80, 1024);

    // ---- k1: encoder real (80 steps) ----
    hipLaunchKernelGGL(coop_enc80, dim3(256), dim3(512), 0, stream,
                       WencF, Xbig, hfragE, enc_seq, cglobE, barE1);

    // ---- Xwarm + EW2 projections (need enc_seq) ----
    big3(enc_seq, 1024, dec_W_ih, 2048, Xbig, 4096, bdec, 5120, 4096, 1024);
    big3(enc_seq, 1024, att_W2 + 1024, 2048, EW2, 1024, zb, 5120, 1024, 1024);

    // ---- k3: enc-pad || dec warm-up (80 steps, overlapped) ----
    hipLaunchKernelGGL(coop_padwarm, dim3(256), dim3(512), 0, stream,
                       WencF, WhhDF, benc, Xbig, cglobE,
                       hfragE, hfragD, enc_pad, cglobD, h_fp32, barPE, barPW);

    // ---- k4: attention decode (80 steps, 2 barriers/step) ----
    hipLaunchKernelGGL(coop_dec80, dim3(256), dim3(512), 0, stream,
                       WihcF, WhhDF, att_W1, EW2, S_g, ctxS, S_log,
                       enc_pad, prelu_w, h_fp32, cglobD,
                       hfragD, ctxfrag, h_all, gsum, barD);

    // ---- final vocab projection (NS=1, output-facing) ----
    {
        dim3 g((20000 + 127) / 128, (5120 + 127) / 128);
        hipLaunchKernelGGL((gemm_mfma_split<1>), g, dim3(256), 0, stream,
                           h_all, 1024, out_emb_W, 1024, out, 20000, out_emb_b, 5120, 20000, 1024);
    }
}